// Round 7
// baseline (4999.180 us; speedup 1.0000x reference)
//
#include <hip/hip_runtime.h>

// ---------------------------------------------------------------------------
// SubtasksRecurrence: T=128 sequential steps, B=256 independent rows.
// R7: 128 blocks x 512 threads (8 waves = 2/SIMD), 2 rows/block.
//     Wave-group A (tid<256): gi-stream (W_ih . s, rows packed v2f) + full
//     tail for row0. Group B: gh-stream (W_hh . h) + tail for row1.
//     The two groups are independent instruction streams per SIMD -> mutual
//     latency hiding. gi/gh exchanged via LDS. 4 barriers/step.
// ZERO arithmetic reordering vs R6/R3 (passed, absmax 0.0078125): identical
// k-ascending chains, identical gi+gh combine order, identical reductions.
// ---------------------------------------------------------------------------

#define RNG_PARTITIONABLE 1

#define T_STEPS 128
#define B_ROWS  256
#define TOT     338
#define CONV    4096
#define LDWF    4161   // W_f row stride (CONV + 2S + 1)
#define LDWB    4128   // W_beta row stride (CONV + S)

typedef float v2f __attribute__((ext_vector_type(2)));

// ------------------------------- threefry ----------------------------------
__device__ __forceinline__ void tf2x32(unsigned k0, unsigned k1, unsigned c0, unsigned c1,
                                       unsigned &o0, unsigned &o1) {
  const unsigned ks2 = k0 ^ k1 ^ 0x1BD11BDAu;
  unsigned x0 = c0 + k0;
  unsigned x1 = c1 + k1;
#define TFR(r) { x0 += x1; x1 = (x1 << (r)) | (x1 >> (32 - (r))); x1 ^= x0; }
  TFR(13) TFR(15) TFR(26) TFR(6)
  x0 += k1; x1 += ks2 + 1u;
  TFR(17) TFR(29) TFR(16) TFR(24)
  x0 += ks2; x1 += k0 + 2u;
  TFR(13) TFR(15) TFR(26) TFR(6)
  x0 += k0; x1 += k1 + 3u;
  TFR(17) TFR(29) TFR(16) TFR(24)
  x0 += k1; x1 += ks2 + 4u;
  TFR(13) TFR(15) TFR(26) TFR(6)
  x0 += ks2; x1 += k0 + 5u;
#undef TFR
  o0 = x0; o1 = x1;
}

__device__ __forceinline__ void rng_key(unsigned j, unsigned &k0, unsigned &k1) {
#if RNG_PARTITIONABLE
  tf2x32(0u, 42u, 0u, j, k0, k1);
#else
  unsigned w[2];
  for (int q = 0; q < 2; ++q) {
    unsigned i = 2u*j + (unsigned)q, a, b;
    if (i < 256u) { tf2x32(0u, 42u, i, 256u + i, a, b); w[q] = a; }
    else          { tf2x32(0u, 42u, i - 256u, i, a, b); w[q] = b; }
  }
  k0 = w[0]; k1 = w[1];
#endif
}

__device__ __forceinline__ unsigned rng_bits(unsigned k0, unsigned k1, unsigned idx, unsigned total) {
#if RNG_PARTITIONABLE
  unsigned o0, o1;
  tf2x32(k0, k1, 0u, idx, o0, o1);
  return o0 ^ o1;
#else
  unsigned half = total >> 1, o0, o1;
  if (idx < half) { tf2x32(k0, k1, idx, half + idx, o0, o1); return o0; }
  else            { tf2x32(k0, k1, idx - half, idx, o0, o1); return o1; }
#endif
}

__device__ __forceinline__ float gumbel_from_bits(unsigned bits) {
  float u0 = __uint_as_float(0x3f800000u | (bits >> 9)) - 1.0f;
  float u  = fmaxf(u0, 1.17549435e-38f);
  return -logf(-logf(u));
}

// ------------------------------ small kernels ------------------------------
__global__ __launch_bounds__(256) void rng_k(float* __restrict__ ggum, float* __restrict__ bgum) {
  unsigned tid = blockIdx.x * 256u + threadIdx.x;
  const unsigned NG = T_STEPS * B_ROWS * 16;
  const unsigned NB = T_STEPS * B_ROWS * 2;
  if (tid < NG) {
    unsigned t = tid / (B_ROWS * 16);
    unsigned i = tid % (B_ROWS * 16);
    unsigned k0, k1; rng_key(2u * t, k0, k1);
    ggum[tid] = gumbel_from_bits(rng_bits(k0, k1, i, B_ROWS * 16));
  } else if (tid < NG + NB) {
    unsigned q = tid - NG;
    unsigned t = q / (B_ROWS * 2);
    unsigned i = q % (B_ROWS * 2);
    unsigned k0, k1; rng_key(2u * t + 1u, k0, k1);
    bgum[q] = gumbel_from_bits(rng_bits(k0, k1, i, B_ROWS * 2));
  }
}

// WI2[(k2*3+p)*256+o] = (W_ih[p*256+o][2k2], W_ih[p*256+o][2k2+1]); WH2 same for W_hh
__global__ __launch_bounds__(256) void prep_k(const float* __restrict__ W_ih,
                                              const float* __restrict__ W_hh,
                                              float2* __restrict__ WI2,
                                              float2* __restrict__ WH2) {
  int i = blockIdx.x * 256 + threadIdx.x;   // 0..98303
  int o = i & 255, q = i >> 8;              // q 0..383
  int k2 = q / 3, p = q - 3 * k2;
  int col = p * 256 + o;
  WI2[i] = make_float2(W_ih[(size_t)col * 256 + 2 * k2], W_ih[(size_t)col * 256 + 2 * k2 + 1]);
  WH2[i] = make_float2(W_hh[(size_t)col * 256 + 2 * k2], W_hh[(size_t)col * 256 + 2 * k2 + 1]);
}

__device__ __forceinline__ float waveRed(float v) {
  v += __shfl_down(v, 32, 64);
  v += __shfl_down(v, 16, 64);
  v += __shfl_down(v, 8, 64);
  v += __shfl_down(v, 4, 64);
  v += __shfl_down(v, 2, 64);
  v += __shfl_down(v, 1, 64);
  return v;
}

__global__ __launch_bounds__(256) void bx_k(const float* __restrict__ obs,
                                            const float* __restrict__ W_beta,
                                            const float* __restrict__ b_beta,
                                            float* __restrict__ bxv) {
  int m = blockIdx.x, tid = threadIdx.x;
  const float* row = obs + (size_t)m * CONV;
  float p0 = 0.f, p1 = 0.f;
  for (int i = tid; i < CONV; i += 256) {
    float o = row[i];
    p0 = fmaf(o, W_beta[i], p0);
    p1 = fmaf(o, W_beta[LDWB + i], p1);
  }
  p0 = waveRed(p0); p1 = waveRed(p1);
  __shared__ float sc[2][4];
  int w = tid >> 6;
  if ((tid & 63) == 0) { sc[0][w] = p0; sc[1][w] = p1; }
  __syncthreads();
  if (tid == 0) bxv[(size_t)m * 2 + 0] = sc[0][0] + sc[0][1] + sc[0][2] + sc[0][3] + b_beta[0];
  if (tid == 1) bxv[(size_t)m * 2 + 1] = sc[1][0] + sc[1][1] + sc[1][2] + sc[1][3] + b_beta[1];
}

// ------------------------------- big GEMM ----------------------------------
struct __attribute__((packed, aligned(4))) F4 { float x, y, z, w; };

__global__ __launch_bounds__(256) void gemm1_k(const float* __restrict__ A,
                                               const float* __restrict__ W,
                                               const float* __restrict__ bias,
                                               float* __restrict__ C1) {
  __shared__ __align__(16) float As[32][68];
  __shared__ __align__(16) float Bs[32][68];
  int bid = blockIdx.x;
  int mt = bid & 511, nt = bid >> 9;
  int m0 = mt * 64, n0 = nt * 64;
  int tid = threadIdx.x;
  int tm = tid & 15, tn = tid >> 4;
  int lr = tid >> 2;
  int lc = (tid & 3) * 8;
  v2f acc[4][2];
#pragma unroll
  for (int i = 0; i < 4; ++i) { acc[i][0] = (v2f){0.f, 0.f}; acc[i][1] = (v2f){0.f, 0.f}; }
  for (int k0 = 0; k0 < CONV; k0 += 32) {
    F4 a0 = *(const F4*)(A + (size_t)(m0 + lr) * CONV + k0 + lc);
    F4 a1 = *(const F4*)(A + (size_t)(m0 + lr) * CONV + k0 + lc + 4);
    F4 b0 = *(const F4*)(W + (size_t)(n0 + lr) * LDWF + k0 + lc);
    F4 b1 = *(const F4*)(W + (size_t)(n0 + lr) * LDWF + k0 + lc + 4);
    __syncthreads();
    As[lc + 0][lr] = a0.x; As[lc + 1][lr] = a0.y; As[lc + 2][lr] = a0.z; As[lc + 3][lr] = a0.w;
    As[lc + 4][lr] = a1.x; As[lc + 5][lr] = a1.y; As[lc + 6][lr] = a1.z; As[lc + 7][lr] = a1.w;
    Bs[lc + 0][lr] = b0.x; Bs[lc + 1][lr] = b0.y; Bs[lc + 2][lr] = b0.z; Bs[lc + 3][lr] = b0.w;
    Bs[lc + 4][lr] = b1.x; Bs[lc + 5][lr] = b1.y; Bs[lc + 6][lr] = b1.z; Bs[lc + 7][lr] = b1.w;
    __syncthreads();
#pragma unroll
    for (int kk = 0; kk < 32; ++kk) {
      const float4 av = *(const float4*)&As[kk][tm * 4];
      const float4 bv = *(const float4*)&Bs[kk][tn * 4];
      const v2f bl = (v2f){bv.x, bv.y};
      const v2f bh = (v2f){bv.z, bv.w};
      const float aa[4] = {av.x, av.y, av.z, av.w};
#pragma unroll
      for (int i = 0; i < 4; ++i) {
        v2f ax = (v2f){aa[i], aa[i]};
        acc[i][0] = __builtin_elementwise_fma(ax, bl, acc[i][0]);
        acc[i][1] = __builtin_elementwise_fma(ax, bh, acc[i][1]);
      }
    }
  }
  const int mrow = m0 + tm * 4;
  const int ncol = n0 + tn * 4;
  float4 bv4 = *(const float4*)(bias + ncol);
#pragma unroll
  for (int i = 0; i < 4; ++i) {
    float4 v;
    v.x = acc[i][0].x + bv4.x; v.y = acc[i][0].y + bv4.y;
    v.z = acc[i][1].x + bv4.z; v.w = acc[i][1].y + bv4.w;
    *(float4*)(C1 + (size_t)(mrow + i) * 256 + ncol) = v;
  }
}

// ------------------------------ sequential ---------------------------------
// 128 blocks x 512 threads; block owns rows {2b, 2b+1}.
// grp = tid>>8: 0 -> gi-stream + row0 tail, 1 -> gh-stream + row1 tail.
__global__ __launch_bounds__(512, 1) void seq_k(
    const float* __restrict__ hx0, const float* __restrict__ task,
    const float* __restrict__ W_f, const float* __restrict__ WI2,
    const float* __restrict__ WH2, const float* __restrict__ b_ih,
    const float* __restrict__ b_hh, const float* __restrict__ W_u,
    const float* __restrict__ b_u, const float* __restrict__ W_s,
    const float* __restrict__ b_s, const float* __restrict__ W_pi,
    const float* __restrict__ b_pi, const float* __restrict__ W_beta,
    const float* __restrict__ C1, const float* __restrict__ bxv,
    const float* __restrict__ ggum, const float* __restrict__ bgum,
    float* __restrict__ out) {
  const int b2 = blockIdx.x;          // 0..127
  const int tid = threadIdx.x;        // 0..511
  const int grp = tid >> 8;           // 0: gi/row0, 1: gh/row1
  const int o = tid & 255;
  const int brow = 2 * b2 + grp;      // this group's row
  const float2* __restrict__ WS = grp ? (const float2*)WH2 : (const float2*)WI2;

  __shared__ float wf_sh[65 * 256];           // 66.6 KB
  __shared__ float wpi_sh[288 * 16];          // 18.4 KB
  __shared__ __align__(16) float4 S4[128];    // (s0[2k],s1[2k],s0[2k+1],s1[2k+1])
  __shared__ __align__(16) float4 H4[128];    // same for h
  __shared__ v2f gex[2][3][256];              // [0]=gi (by GA), [1]=gh (by GB); v2f=(row0,row1)
  __shared__ float M_sh[2][512];
  __shared__ float red4[2][4][4];
  __shared__ float red16[2][4][16];
  __shared__ float p_sh[2][2][16];            // [row][parity][n]
  __shared__ float r_sh[2][2][32];
  __shared__ float g_sh[2][2][32];
  __shared__ float gg_sh[2][16], bg_sh[2][2], bx_sh[2][2];
  __shared__ float wb_sh[2][32], bpi_sh[16];

  // ---- one-time init ----
  for (int i = tid; i < 65 * 256; i += 512) {
    int oo = i / 65, j = i % 65;
    wf_sh[i] = W_f[(size_t)oo * LDWF + CONV + j];
  }
  for (int i = tid; i < 288 * 16; i += 512) wpi_sh[i] = W_pi[i];
  float hold = hx0[brow * TOT + 48 + o];
  ((float*)&H4[o >> 1])[(o & 1) * 2 + grp] = hold;
  if (o < 16) p_sh[grp][0][o] = hx0[brow * TOT + o];
  if (o < 32) {
    r_sh[grp][0][o] = hx0[brow * TOT + 16 + o];
    g_sh[grp][0][o] = hx0[brow * TOT + 304 + o];
  }
  M_sh[grp][o]       = task[(size_t)brow * 512 + o];
  M_sh[grp][256 + o] = task[(size_t)brow * 512 + 256 + o];
  if (tid < 32) {
    wb_sh[0][tid] = W_beta[CONV + tid];
    wb_sh[1][tid] = W_beta[LDWB + CONV + tid];
  }
  if (tid >= 32 && tid < 48) bpi_sh[tid - 32] = b_pi[tid - 32];
  float bnew = hx0[brow * TOT + 336];

  const float bih_r = b_ih[o], bih_z = b_ih[256 + o], bih_n = b_ih[512 + o];
  const float bhh_r = b_hh[o], bhh_z = b_hh[256 + o], bhh_n = b_hh[512 + o];
  const float wu_s = W_u[o], wu_h = W_u[256 + o];
  const float ws0 = W_s[o], ws1 = W_s[256 + o], ws2 = W_s[512 + o];
  const float bu0 = b_u[0], bs0 = b_s[0], bs1 = b_s[1], bs2 = b_s[2];
  __syncthreads();

  // ---- t=0 s-compute (chain identical to R6's phase-1) ----
  float sacc;
  {
    const float* wfr = wf_sh + o * 65;
    sacc = C1[(size_t)brow * 256 + o];
#pragma unroll
    for (int j = 0; j < 32; ++j) sacc = fmaf(r_sh[grp][0][j], wfr[j], sacc);
#pragma unroll
    for (int j = 0; j < 32; ++j) sacc = fmaf(g_sh[grp][0][j], wfr[32 + j], sacc);
    sacc = fmaf(bnew, wfr[64], sacc);
    ((float*)&S4[o >> 1])[(o & 1) * 2 + grp] = sacc;
  }
  __syncthreads();

  for (int t = 0; t < T_STEPS; ++t) {
    const int pp = t & 1, np = pp ^ 1;

    // ---- P0: prefetches ----
    int tn2 = (t + 1 < T_STEPS) ? t + 1 : t;
    float c1n = C1[((size_t)tn2 * 256 + brow) * 256 + o];
    if (o < 16) gg_sh[grp][o] = ggum[((size_t)t * 256 + brow) * 16 + o];
    else if (o < 18) bg_sh[grp][o - 16] = bgum[((size_t)t * 256 + brow) * 2 + (o - 16)];
    else if (o < 20) bx_sh[grp][o - 18] = bxv[((size_t)t * 256 + brow) * 2 + (o - 18)];

    // ---- P1: group-specific weight stream (gi for GA over S4, gh for GB over H4) ----
    v2f gr = (v2f){0.f, 0.f}, gz = (v2f){0.f, 0.f}, gn = (v2f){0.f, 0.f};
    {
      const float4* __restrict__ X4 = grp ? H4 : S4;
#pragma unroll 8
      for (int k2 = 0; k2 < 128; ++k2) {
        float2 wr = WS[(size_t)(k2 * 3 + 0) * 256 + o];
        float2 wz = WS[(size_t)(k2 * 3 + 1) * 256 + o];
        float2 wn = WS[(size_t)(k2 * 3 + 2) * 256 + o];
        float4 x = X4[k2];
        v2f xa = (v2f){x.x, x.y};
        v2f xb = (v2f){x.z, x.w};
        gr = __builtin_elementwise_fma(xa, (v2f){wr.x, wr.x}, gr);
        gr = __builtin_elementwise_fma(xb, (v2f){wr.y, wr.y}, gr);
        gz = __builtin_elementwise_fma(xa, (v2f){wz.x, wz.x}, gz);
        gz = __builtin_elementwise_fma(xb, (v2f){wz.y, wz.y}, gz);
        gn = __builtin_elementwise_fma(xa, (v2f){wn.x, wn.x}, gn);
        gn = __builtin_elementwise_fma(xb, (v2f){wn.y, wn.y}, gn);
      }
      gex[grp][0][o] = gr; gex[grp][1][o] = gz; gex[grp][2][o] = gn;
    }
    // c/l partials for this group's row (verbatim R6 order; sacc/hold in regs)
    {
      float pc = fmaf(wu_s, sacc, wu_h * hold);
      float q0 = ws0 * hold, q1 = ws1 * hold, q2 = ws2 * hold;
      pc = waveRed(pc); q0 = waveRed(q0); q1 = waveRed(q1); q2 = waveRed(q2);
      int w4 = (tid >> 6) & 3;
      if ((tid & 63) == 0) { red4[grp][w4][0] = pc; red4[grp][w4][1] = q0; red4[grp][w4][2] = q1; red4[grp][w4][3] = q2; }
    }
    __syncthreads();                                           // B1

    // ---- P2: redundant c,l; GRU for this group's row; p'/r'; logits partials ----
    float c, l0, l1, l2;
    {
      float cs = red4[grp][0][0] + red4[grp][1][0] + red4[grp][2][0] + red4[grp][3][0] + bu0;
      c = 1.0f / (1.0f + expf(-cs));
      float x0 = red4[grp][0][1] + red4[grp][1][1] + red4[grp][2][1] + red4[grp][3][1] + bs0;
      float x1 = red4[grp][0][2] + red4[grp][1][2] + red4[grp][2][2] + red4[grp][3][2] + bs1;
      float x2 = red4[grp][0][3] + red4[grp][1][3] + red4[grp][2][3] + red4[grp][3][3] + bs2;
      float m = fmaxf(x0, fmaxf(x1, x2));
      float e0 = expf(x0 - m), e1 = expf(x1 - m), e2 = expf(x2 - m);
      float es = e0 + e1 + e2;
      l0 = e0 / es; l1 = e1 / es; l2 = e2 / es;
    }
    const float omc = 1.0f - c;
    float gi_r, gi_z, gi_n, gh_r, gh_z, gh_n;
    if (grp == 0) {
      gi_r = gr.x; gi_z = gz.x; gi_n = gn.x;
      gh_r = gex[1][0][o].x; gh_z = gex[1][1][o].x; gh_n = gex[1][2][o].x;
    } else {
      gi_r = gex[0][0][o].y; gi_z = gex[0][1][o].y; gi_n = gex[0][2][o].y;
      gh_r = gr.y; gh_z = gz.y; gh_n = gn.y;
    }
    float hg;
    {
      float rr_ = 1.0f / (1.0f + expf(-(gi_r + bih_r + gh_r + bhh_r)));
      float zz  = 1.0f / (1.0f + expf(-(gi_z + bih_z + gh_z + bhh_z)));
      float nn  = tanhf(gi_n + bih_n + rr_ * (gh_n + bhh_n));
      float hnew = (1.0f - zz) * nn + zz * hold;
      hg = c * hnew + omc * hold;
      ((float*)&H4[o >> 1])[(o & 1) * 2 + grp] = hg;
    }
    float pn[16];
#pragma unroll
    for (int i = 0; i < 16; ++i) {
      float pm = (i > 0) ? p_sh[grp][pp][i - 1] : 0.f;
      float pq = (i < 15) ? p_sh[grp][pp][i + 1] : 0.f;
      pn[i] = l0 * pm + l1 * p_sh[grp][pp][i] + l2 * pq;
    }
    float rv = 0.f;
    if (o < 32) {
      float a = 0.f;
#pragma unroll
      for (int n2 = 0; n2 < 16; ++n2) a = fmaf(pn[n2], M_sh[grp][n2 * 32 + o], a);
      rv = c * a + omc * r_sh[grp][pp][o];
      r_sh[grp][np][o] = rv;
    }
    if (o < 16) p_sh[grp][np][o] = c * pn[o] + omc * p_sh[grp][pp][o];
    // logits partials (verbatim R6 per-row order)
    {
      float pv[16];
#pragma unroll
      for (int o2 = 0; o2 < 16; ++o2) pv[o2] = hg * wpi_sh[o2 * 288 + o];
      if (o < 32) {
#pragma unroll
        for (int o2 = 0; o2 < 16; ++o2) pv[o2] = fmaf(rv, wpi_sh[o2 * 288 + 256 + o], pv[o2]);
      }
#pragma unroll
      for (int o2 = 0; o2 < 16; ++o2) pv[o2] = waveRed(pv[o2]);
      int w4 = (tid >> 6) & 3;
      if ((tid & 63) == 0) {
#pragma unroll
        for (int o2 = 0; o2 < 16; ++o2) red16[grp][w4][o2] = pv[o2];
      }
    }
    hold = hg;
    __syncthreads();                                           // B2

    // ---- P3: redundant g-sampling; g' write ----
    int gidx = 0;
    float lpg;
    {
      float lg[16];
#pragma unroll
      for (int n2 = 0; n2 < 16; ++n2)
        lg[n2] = red16[grp][0][n2] + red16[grp][1][n2] + red16[grp][2][n2] + red16[grp][3][n2] + bpi_sh[n2];
      float best = -3.402823466e+38f;
      for (int n2 = 0; n2 < 16; ++n2) {
        float v = lg[n2] + gg_sh[grp][n2];
        if (v > best) { best = v; gidx = n2; }
      }
      float mx = lg[0];
      for (int n2 = 1; n2 < 16; ++n2) mx = fmaxf(mx, lg[n2]);
      float se = 0.f;
      for (int n2 = 0; n2 < 16; ++n2) se += expf(lg[n2] - mx);
      lpg = lg[gidx] - mx - logf(se);
    }
    if (o < 32) g_sh[grp][np][o] = c * M_sh[grp][gidx * 32 + o] + omc * g_sh[grp][pp][o];
    __syncthreads();                                           // B3

    // ---- P4: redundant b-sampling; next-step s; outputs ----
    float lpt;
    {
      float lb0 = bx_sh[grp][0], lb1 = bx_sh[grp][1];
      for (int s2 = 0; s2 < 32; ++s2) {
        float gv = g_sh[grp][np][s2];
        lb0 = fmaf(gv, wb_sh[0][s2], lb0);
        lb1 = fmaf(gv, wb_sh[1][s2], lb1);
      }
      int bidx = ((lb1 + bg_sh[grp][1]) > (lb0 + bg_sh[grp][0])) ? 1 : 0;
      float mb = fmaxf(lb0, lb1);
      float seb = expf(lb0 - mb) + expf(lb1 - mb);
      bnew = (float)bidx;
      lpt = lpg + ((bidx ? lb1 : lb0) - mb - logf(seb));
    }
    // next-step s (chain identical to R6)
    {
      const float* wfr = wf_sh + o * 65;
      sacc = c1n;
#pragma unroll
      for (int j = 0; j < 32; ++j) sacc = fmaf(r_sh[grp][np][j], wfr[j], sacc);
#pragma unroll
      for (int j = 0; j < 32; ++j) sacc = fmaf(g_sh[grp][np][j], wfr[32 + j], sacc);
      sacc = fmaf(bnew, wfr[64], sacc);
      ((float*)&S4[o >> 1])[(o & 1) * 2 + grp] = sacc;
    }
    // outputs: this group's row x [p16, r32, h256, g32, b1, lp1]
    {
      size_t base = ((size_t)t * 256 + brow) * TOT;
      for (int j = o; j < TOT; j += 256) {
        float v;
        if (j < 16) v = p_sh[grp][np][j];
        else if (j < 48) v = r_sh[grp][np][j - 16];
        else if (j < 304) { int hh = j - 48; v = ((const float*)&H4[hh >> 1])[(hh & 1) * 2 + grp]; }
        else if (j < 336) v = g_sh[grp][np][j - 304];
        else if (j == 336) v = bnew;
        else v = lpt;
        out[base + j] = v;
      }
    }
    __syncthreads();                                           // B4
  }
}

// ------------------------------ host launch --------------------------------
extern "C" void kernel_launch(void* const* d_in, const int* in_sizes, int n_in,
                              void* d_out, int out_size, void* d_ws, size_t ws_size,
                              hipStream_t stream) {
  const float* obs    = (const float*)d_in[0];
  const float* task   = (const float*)d_in[1];
  const float* hx0    = (const float*)d_in[2];
  const float* W_ih   = (const float*)d_in[3];
  const float* W_hh   = (const float*)d_in[4];
  const float* b_ih   = (const float*)d_in[5];
  const float* b_hh   = (const float*)d_in[6];
  const float* W_f    = (const float*)d_in[7];
  const float* b_f    = (const float*)d_in[8];
  const float* W_u    = (const float*)d_in[9];
  const float* b_u    = (const float*)d_in[10];
  const float* W_s    = (const float*)d_in[11];
  const float* b_s    = (const float*)d_in[12];
  const float* W_pi   = (const float*)d_in[13];
  const float* b_pi   = (const float*)d_in[14];
  const float* W_beta = (const float*)d_in[15];
  const float* b_beta = (const float*)d_in[16];

  char* ws = (char*)d_ws;
  size_t off = 0;
  auto take = [&](size_t bytes) {
    size_t r = off;
    off += (bytes + 255) & ~(size_t)255;
    return r;
  };
  size_t off_WI2  = take((size_t)98304 * 8);
  size_t off_WH2  = take((size_t)98304 * 8);
  size_t off_ggum = take((size_t)T_STEPS * B_ROWS * 16 * 4);
  size_t off_bgum = take((size_t)T_STEPS * B_ROWS * 2 * 4);
  size_t off_bx   = take((size_t)T_STEPS * B_ROWS * 2 * 4);
  size_t off_C1   = take((size_t)T_STEPS * B_ROWS * 256 * 4);
  if (off > ws_size) return;

  float* WI2  = (float*)(ws + off_WI2);
  float* WH2  = (float*)(ws + off_WH2);
  float* ggum = (float*)(ws + off_ggum);
  float* bgum = (float*)(ws + off_bgum);
  float* bxv  = (float*)(ws + off_bx);
  float* C1   = (float*)(ws + off_C1);

  hipLaunchKernelGGL(prep_k, dim3(384), dim3(256), 0, stream, W_ih, W_hh,
                     (float2*)WI2, (float2*)WH2);
  hipLaunchKernelGGL(rng_k, dim3(2304), dim3(256), 0, stream, ggum, bgum);
  hipLaunchKernelGGL(gemm1_k, dim3(2048), dim3(256), 0, stream, obs, W_f, b_f, C1);
  hipLaunchKernelGGL(bx_k, dim3(32768), dim3(256), 0, stream, obs, W_beta, b_beta, bxv);
  hipLaunchKernelGGL(seq_k, dim3(128), dim3(512), 0, stream,
                     hx0, task, W_f, WI2, WH2, b_ih, b_hh, W_u, b_u, W_s, b_s, W_pi, b_pi,
                     W_beta, C1, bxv, ggum, bgum, (float*)d_out);
}